// Round 1
// baseline (399.546 us; speedup 1.0000x reference)
//
#include <hip/hip_runtime.h>
#include <math.h>

#define DIM 384
#define NH 6
#define DH 64
#define B_ 2
#define S_ 2048
#define EPS 1e-6f
#define LN_EPS 1e-5f
#define G3 (3*DIM)   // 1152

__device__ __forceinline__ float logsig(float x){
    return fminf(x, 0.f) - log1pf(expf(-fabsf(x)));
}

// ---------------- Kernel 1: gate projections ----------------
// One wave (64 lanes) per (b,s) position; computes all NH igate + NH fgate
// dot products of length 3*DIM, butterfly-reduces, writes ig and log_sigmoid(fg).
__global__ __launch_bounds__(256) void gates_kernel(
    const float* __restrict__ q, const float* __restrict__ k, const float* __restrict__ v,
    const float* __restrict__ iw, const float* __restrict__ ib,
    const float* __restrict__ fw, const float* __restrict__ fb,
    float* __restrict__ ig_out, float* __restrict__ lf_out) {
    int wave = (blockIdx.x * 256 + threadIdx.x) >> 6;
    int lane = threadIdx.x & 63;
    int b = wave / S_, s = wave % S_;
    size_t base = ((size_t)b * S_ + s) * DIM;
    float aI[NH], aF[NH];
    #pragma unroll
    for (int h = 0; h < NH; h++){ aI[h] = 0.f; aF[h] = 0.f; }
    for (int e = lane; e < G3; e += 64) {
        float x;
        if (e < DIM)        x = q[base + e];
        else if (e < 2*DIM) x = k[base + e - DIM];
        else                x = v[base + e - 2*DIM];
        #pragma unroll
        for (int h = 0; h < NH; h++){
            aI[h] = fmaf(x, iw[h*G3 + e], aI[h]);
            aF[h] = fmaf(x, fw[h*G3 + e], aF[h]);
        }
    }
    #pragma unroll
    for (int h = 0; h < NH; h++){
        #pragma unroll
        for (int off = 32; off >= 1; off >>= 1){
            aI[h] += __shfl_xor(aI[h], off, 64);
            aF[h] += __shfl_xor(aF[h], off, 64);
        }
    }
    if (lane == 0) {
        #pragma unroll
        for (int h = 0; h < NH; h++){
            ig_out[((size_t)b*NH + h)*S_ + s] = aI[h] + ib[h];
            lf_out[((size_t)b*NH + h)*S_ + s] = logsig(aF[h] + fb[h]);
        }
    }
}

// ---------------- Kernel 2: cumsum of log-sigmoid(fgate) ----------------
// One block per (b,h). cum[s] = inclusive cumsum of lf over s (== lfc[s+1]).
__global__ __launch_bounds__(256) void scan_kernel(const float* __restrict__ lf,
                                                   float* __restrict__ cum){
    int bh = blockIdx.x;
    const float* src = lf + (size_t)bh * S_;
    float* dst = cum + (size_t)bh * S_;
    int tid = threadIdx.x;
    float loc[8];
    float run = 0.f;
    #pragma unroll
    for (int j = 0; j < 8; j++){ run += src[tid*8 + j]; loc[j] = run; }
    __shared__ float sm[256];
    sm[tid] = run;
    __syncthreads();
    float total = run;
    for (int off = 1; off < 256; off <<= 1){
        float vv = (tid >= off) ? sm[tid - off] : 0.f;
        __syncthreads();
        sm[tid] += vv;
        __syncthreads();
    }
    float excl = sm[tid] - total;
    #pragma unroll
    for (int j = 0; j < 8; j++) dst[tid*8 + j] = excl + loc[j];
}

// ---------------- Kernel 3: fused causal mLSTM attention + head LayerNorm ----
// Block = 256 threads as 16x16 grid; each thread owns a 4x4 sub-tile.
// Per (b,h,s-tile of 64 rows): iterate k/v tiles of 64 cols (causal),
// flash-style online max/sum rescaling. q,k stored TRANSPOSED in LDS
// ([kk][r], stride 68) -> both matmul read phases are conflict-free b128.
// P reuses the k-tile LDS buffer. Epilogue: normalizer + LayerNorm + scale.
__global__ __launch_bounds__(256) void mlstm_kernel(
    const float* __restrict__ q, const float* __restrict__ k, const float* __restrict__ v,
    const float* __restrict__ ig, const float* __restrict__ cum,
    const float* __restrict__ w, float* __restrict__ out) {
    __shared__ float qt[64][68];   // q^T tile: qt[kk][r] = q[r][kk]/8
    __shared__ float kt[64][68];   // k^T tile, later reused as P^T: pt[t][r]
    __shared__ float vs[64][68];   // v tile: vs[t][dh]
    int bh = blockIdx.y;
    int b = bh / NH, h = bh % NH;
    int st = (gridDim.x - 1) - blockIdx.x;   // longest blocks first
    int s0 = st * 64;
    int tid = threadIdx.x;
    int ty = tid >> 4, tx = tid & 15;

    const float* qbase = q + (size_t)b * S_ * DIM + h * DH;
    const float* kbase = k + (size_t)b * S_ * DIM + h * DH;
    const float* vbase = v + (size_t)b * S_ * DIM + h * DH;
    const float* igb = ig + (size_t)bh * S_;
    const float* cmb = cum + (size_t)bh * S_;

    // load q tile (transposed, pre-scaled by 1/sqrt(DH)=0.125)
    #pragma unroll
    for (int i = 0; i < 4; i++){
        int idx = tid + i*256;
        int row = idx >> 4;
        int c4  = (idx & 15) * 4;
        float4 t4 = *(const float4*)(qbase + (size_t)(s0 + row)*DIM + c4);
        qt[c4+0][row] = t4.x * 0.125f;
        qt[c4+1][row] = t4.y * 0.125f;
        qt[c4+2][row] = t4.z * 0.125f;
        qt[c4+3][row] = t4.w * 0.125f;
    }
    float m_r[4], b_r[4], acc[4][4];
    #pragma unroll
    for (int i = 0; i < 4; i++){
        m_r[i] = -INFINITY; b_r[i] = 0.f;
        #pragma unroll
        for (int j = 0; j < 4; j++) acc[i][j] = 0.f;
    }
    float cq[4];
    #pragma unroll
    for (int i = 0; i < 4; i++) cq[i] = cmb[s0 + 4*ty + i];

    for (int t0 = 0; t0 <= s0; t0 += 64) {
        __syncthreads();   // prev iter done reading kt(P) & vs
        #pragma unroll
        for (int i = 0; i < 4; i++){
            int idx = tid + i*256;
            int row = idx >> 4;
            int c4  = (idx & 15) * 4;
            float4 k4 = *(const float4*)(kbase + (size_t)(t0 + row)*DIM + c4);
            kt[c4+0][row] = k4.x; kt[c4+1][row] = k4.y;
            kt[c4+2][row] = k4.z; kt[c4+3][row] = k4.w;
            float4 v4 = *(const float4*)(vbase + (size_t)(t0 + row)*DIM + c4);
            *(float4*)&vs[row][c4] = v4;
        }
        __syncthreads();
        // ---- matmul1: S = (q/8) @ k^T  (outer-product over kk) ----
        float sij[4][4];
        #pragma unroll
        for (int i = 0; i < 4; i++)
            #pragma unroll
            for (int j = 0; j < 4; j++) sij[i][j] = 0.f;
        #pragma unroll 4
        for (int kk = 0; kk < 64; kk++){
            float4 a4 = *(const float4*)&qt[kk][4*ty];
            float4 b4 = *(const float4*)&kt[kk][4*tx];
            float af[4] = {a4.x, a4.y, a4.z, a4.w};
            float bf[4] = {b4.x, b4.y, b4.z, b4.w};
            #pragma unroll
            for (int i = 0; i < 4; i++)
                #pragma unroll
                for (int j = 0; j < 4; j++)
                    sij[i][j] = fmaf(af[i], bf[j], sij[i][j]);
        }
        // ---- elementwise: decay matrix + online rescale ----
        float cumk[4], igk[4];
        #pragma unroll
        for (int j = 0; j < 4; j++){
            int col = t0 + 4*tx + j;
            cumk[j] = cmb[col];
            igk[j]  = igb[col];
        }
        bool diag = (t0 == s0);
        float dv[4][4], tmax[4];
        #pragma unroll
        for (int i = 0; i < 4; i++){
            tmax[i] = -INFINITY;
            int row = s0 + 4*ty + i;
            #pragma unroll
            for (int j = 0; j < 4; j++){
                int col = t0 + 4*tx + j;
                float d = cq[i] - cumk[j] + igk[j];
                if (diag && col > row) d = -INFINITY;
                dv[i][j] = d;
                tmax[i] = fmaxf(tmax[i], d);
            }
        }
        #pragma unroll
        for (int i = 0; i < 4; i++){
            #pragma unroll
            for (int off = 8; off >= 1; off >>= 1)
                tmax[i] = fmaxf(tmax[i], __shfl_xor(tmax[i], off, 64));
        }
        float p[4][4];
        #pragma unroll
        for (int i = 0; i < 4; i++){
            float mn = fmaxf(m_r[i], tmax[i]);
            float sc = expf(m_r[i] - mn);   // first tile: expf(-inf)=0
            m_r[i] = mn;
            float rs = 0.f;
            #pragma unroll
            for (int j = 0; j < 4; j++){
                float pv = sij[i][j] * expf(dv[i][j] - mn);
                p[i][j] = pv;
                rs += pv;
            }
            #pragma unroll
            for (int off = 8; off >= 1; off >>= 1)
                rs += __shfl_xor(rs, off, 64);
            b_r[i] = b_r[i] * sc + rs;
            #pragma unroll
            for (int j = 0; j < 4; j++) acc[i][j] *= sc;
        }
        __syncthreads();   // all done reading kt as K
        #pragma unroll
        for (int i = 0; i < 4; i++)
            #pragma unroll
            for (int j = 0; j < 4; j++)
                kt[4*tx + j][4*ty + i] = p[i][j];   // pt[t][r]
        __syncthreads();
        // ---- matmul2: acc += P @ V (outer-product over t) ----
        #pragma unroll 4
        for (int t = 0; t < 64; t++){
            float4 a4 = *(const float4*)&kt[t][4*ty];
            float4 b4 = *(const float4*)&vs[t][4*tx];
            float af[4] = {a4.x, a4.y, a4.z, a4.w};
            float bf[4] = {b4.x, b4.y, b4.z, b4.w};
            #pragma unroll
            for (int i = 0; i < 4; i++)
                #pragma unroll
                for (int j = 0; j < 4; j++)
                    acc[i][j] = fmaf(af[i], bf[j], acc[i][j]);
        }
    }
    // ---- epilogue: normalizer + per-head LayerNorm + scale ----
    #pragma unroll
    for (int i = 0; i < 4; i++){
        float nrm = fmaxf(fabsf(b_r[i]), expf(-m_r[i]));
        float inv = 1.f / (nrm + EPS);
        float x[4];
        #pragma unroll
        for (int j = 0; j < 4; j++) x[j] = acc[i][j] * inv;
        float s1 = 0.f, s2 = 0.f;
        #pragma unroll
        for (int j = 0; j < 4; j++){ s1 += x[j]; s2 += x[j]*x[j]; }
        #pragma unroll
        for (int off = 8; off >= 1; off >>= 1){
            s1 += __shfl_xor(s1, off, 64);
            s2 += __shfl_xor(s2, off, 64);
        }
        float mean = s1 * (1.f/64.f);
        float var  = s2 * (1.f/64.f) - mean*mean;
        float rstd = rsqrtf(var + LN_EPS);
        float4 o;
        o.x = (x[0]-mean)*rstd*(1.f + w[h*DH + 4*tx + 0]);
        o.y = (x[1]-mean)*rstd*(1.f + w[h*DH + 4*tx + 1]);
        o.z = (x[2]-mean)*rstd*(1.f + w[h*DH + 4*tx + 2]);
        o.w = (x[3]-mean)*rstd*(1.f + w[h*DH + 4*tx + 3]);
        *(float4*)(out + ((size_t)b*S_ + s0 + 4*ty + i)*DIM + h*DH + 4*tx) = o;
    }
}

extern "C" void kernel_launch(void* const* d_in, const int* in_sizes, int n_in,
                              void* d_out, int out_size, void* d_ws, size_t ws_size,
                              hipStream_t stream) {
    const float* q  = (const float*)d_in[0];
    const float* k  = (const float*)d_in[1];
    const float* v  = (const float*)d_in[2];
    const float* iw = (const float*)d_in[3];
    const float* ib = (const float*)d_in[4];
    const float* fw = (const float*)d_in[5];
    const float* fb = (const float*)d_in[6];
    const float* w  = (const float*)d_in[7];
    float* out = (float*)d_out;

    float* ig  = (float*)d_ws;                 // B*NH*S
    float* lf  = ig  + (size_t)B_*NH*S_;       // B*NH*S
    float* cum = lf  + (size_t)B_*NH*S_;       // B*NH*S

    gates_kernel<<<B_*S_/4, 256, 0, stream>>>(q, k, v, iw, ib, fw, fb, ig, lf);
    scan_kernel<<<B_*NH, 256, 0, stream>>>(lf, cum);
    mlstm_kernel<<<dim3(S_/64, B_*NH), 256, 0, stream>>>(q, k, v, ig, cum, w, out);
}

// Round 4
// 235.638 us; speedup vs baseline: 1.6956x; 1.6956x over previous
//
#include <hip/hip_runtime.h>
#include <math.h>

#define DIM 384
#define NH 6
#define DH 64
#define B_ 2
#define S_ 2048
#define EPS 1e-6f
#define LN_EPS 1e-5f
#define G3 (3*DIM)   // 1152
#define LOG2E 1.44269504f
#define KSTR 72      // LDS row stride (ushort): 144 B -> 4-bank rotate/row

typedef __attribute__((ext_vector_type(8))) short bf16x8;
typedef __attribute__((ext_vector_type(4))) short bf16x4;
typedef __attribute__((ext_vector_type(4))) float f32x4;

__device__ __forceinline__ unsigned short f2bf(float f){
    unsigned int u = __float_as_uint(f);
    u += 0x7fff + ((u >> 16) & 1);   // round-to-nearest-even
    return (unsigned short)(u >> 16);
}

__device__ __forceinline__ float logsig(float x){
    return fminf(x, 0.f) - log1pf(expf(-fabsf(x)));
}

// ---------------- Kernel 1: gate projections ----------------
__global__ __launch_bounds__(256) void gates_kernel(
    const float* __restrict__ q, const float* __restrict__ k, const float* __restrict__ v,
    const float* __restrict__ iw, const float* __restrict__ ib,
    const float* __restrict__ fw, const float* __restrict__ fb,
    float* __restrict__ ig_out, float* __restrict__ lf_out) {
    int wave = (blockIdx.x * 256 + threadIdx.x) >> 6;
    int lane = threadIdx.x & 63;
    int b = wave / S_, s = wave % S_;
    size_t base = ((size_t)b * S_ + s) * DIM;
    float aI[NH], aF[NH];
    #pragma unroll
    for (int h = 0; h < NH; h++){ aI[h] = 0.f; aF[h] = 0.f; }
    for (int e = lane; e < G3; e += 64) {
        float x;
        if (e < DIM)        x = q[base + e];
        else if (e < 2*DIM) x = k[base + e - DIM];
        else                x = v[base + e - 2*DIM];
        #pragma unroll
        for (int h = 0; h < NH; h++){
            aI[h] = fmaf(x, iw[h*G3 + e], aI[h]);
            aF[h] = fmaf(x, fw[h*G3 + e], aF[h]);
        }
    }
    #pragma unroll
    for (int h = 0; h < NH; h++){
        #pragma unroll
        for (int off = 32; off >= 1; off >>= 1){
            aI[h] += __shfl_xor(aI[h], off, 64);
            aF[h] += __shfl_xor(aF[h], off, 64);
        }
    }
    if (lane == 0) {
        #pragma unroll
        for (int h = 0; h < NH; h++){
            ig_out[((size_t)b*NH + h)*S_ + s] = aI[h] + ib[h];
            lf_out[((size_t)b*NH + h)*S_ + s] = logsig(aF[h] + fb[h]);
        }
    }
}

// ---------------- Kernel 2: cumsum of log-sigmoid(fgate) ----------------
__global__ __launch_bounds__(256) void scan_kernel(const float* __restrict__ lf,
                                                   float* __restrict__ cum){
    int bh = blockIdx.x;
    const float* src = lf + (size_t)bh * S_;
    float* dst = cum + (size_t)bh * S_;
    int tid = threadIdx.x;
    float loc[8];
    float run = 0.f;
    #pragma unroll
    for (int j = 0; j < 8; j++){ run += src[tid*8 + j]; loc[j] = run; }
    __shared__ float sm[256];
    sm[tid] = run;
    __syncthreads();
    float total = run;
    for (int off = 1; off < 256; off <<= 1){
        float vv = (tid >= off) ? sm[tid - off] : 0.f;
        __syncthreads();
        sm[tid] += vv;
        __syncthreads();
    }
    float excl = sm[tid] - total;
    #pragma unroll
    for (int j = 0; j < 8; j++) dst[tid*8 + j] = excl + loc[j];
}

// ---------------- Kernel 3: MFMA flash-mLSTM (transpose-free) ----------------
// Block = 256 = 4 waves; wave wv owns q-rows [s0+16wv, s0+16wv+16).
// Matmul1 computes S^T = MFMA(A=K-block, B=Q-stripe): C-layout holds
// S^T[t=4quad+r][s=lq]. The exp-ed P^T values in those registers are exactly
// the A-operand layout of v_mfma_f32_16x16x16_bf16 (A[m=lq][k=4quad+j]), so
// PV needs NO transpose and NO LDS round-trip. Only cross-thread LDS traffic
// is the barrier-protected tile staging (round-1-proven pattern).
__global__ __launch_bounds__(256) void mlstm_kernel(
    const float* __restrict__ q, const float* __restrict__ k, const float* __restrict__ v,
    const float* __restrict__ ig, const float* __restrict__ cum,
    const float* __restrict__ w, float* __restrict__ out) {
    __shared__ unsigned short kt[64*KSTR];   // K row-major: kt[t][d]
    __shared__ unsigned short vt[64*KSTR];   // V transposed: vt[d][t]
    __shared__ float cumL[64];
    __shared__ float igL[64];

    int bh = blockIdx.y;
    int b = bh / NH, h = bh % NH;
    int s0 = ((gridDim.x - 1) - blockIdx.x) * 64;   // longest blocks first
    int tid = threadIdx.x;
    int wv   = tid >> 6;
    int lane = tid & 63;
    int lq   = lane & 15;
    int quad = lane >> 4;

    const float* qbase = q + (size_t)b*S_*DIM + h*DH;
    const float* kbase = k + (size_t)b*S_*DIM + h*DH;
    const float* vbase = v + (size_t)b*S_*DIM + h*DH;
    const float* igb = ig + (size_t)bh*S_;
    const float* cmb = cum + (size_t)bh*S_;

    int s_glob = s0 + 16*wv + lq;   // the s-row this lane's softmax state tracks

    // Q as B-operand fragments: B[n=lq][k=quad*8+j], rows s0+16wv+lq, x0.125
    bf16x8 qf[2];
    {
        const float* qr = qbase + (size_t)s_glob*DIM;
        #pragma unroll
        for (int ks = 0; ks < 2; ks++){
            float4 a = *(const float4*)(qr + 32*ks + 8*quad);
            float4 c = *(const float4*)(qr + 32*ks + 8*quad + 4);
            bf16x8 t;
            t[0]=(short)f2bf(a.x*0.125f); t[1]=(short)f2bf(a.y*0.125f);
            t[2]=(short)f2bf(a.z*0.125f); t[3]=(short)f2bf(a.w*0.125f);
            t[4]=(short)f2bf(c.x*0.125f); t[5]=(short)f2bf(c.y*0.125f);
            t[6]=(short)f2bf(c.z*0.125f); t[7]=(short)f2bf(c.w*0.125f);
            qf[ks] = t;
        }
    }

    float cq  = cmb[s_glob];
    float m_s = -INFINITY, b_s = 0.f;   // online-softmax state for row s=lq (replicated/quad)
    f32x4 oacc[4];                      // O C-layout: row s=4quad+r, col d=16cg+lq
    #pragma unroll
    for (int cg = 0; cg < 4; cg++) oacc[cg] = (f32x4){0.f,0.f,0.f,0.f};
    float wld[4];
    #pragma unroll
    for (int cg = 0; cg < 4; cg++) wld[cg] = w[h*DH + 16*cg + lq];

    for (int t0 = 0; t0 <= s0; t0 += 64){
        __syncthreads();   // B1: prev iteration done reading kt/vt/cumL/igL
        #pragma unroll
        for (int i = 0; i < 4; i++){
            int idx = tid + 256*i;
            int r = idx >> 4;          // tile row (t)
            int c = (idx & 15) << 2;   // col (d), x4
            float4 k4 = *(const float4*)(kbase + (size_t)(t0 + r)*DIM + c);
            ushort4 kk; kk.x=f2bf(k4.x); kk.y=f2bf(k4.y); kk.z=f2bf(k4.z); kk.w=f2bf(k4.w);
            *(ushort4*)&kt[r*KSTR + c] = kk;
            float4 v4 = *(const float4*)(vbase + (size_t)(t0 + r)*DIM + c);
            vt[(c+0)*KSTR + r] = f2bf(v4.x);
            vt[(c+1)*KSTR + r] = f2bf(v4.y);
            vt[(c+2)*KSTR + r] = f2bf(v4.z);
            vt[(c+3)*KSTR + r] = f2bf(v4.w);
        }
        if (tid < 64){ cumL[tid] = cmb[t0 + tid]; igL[tid] = igb[t0 + tid]; }
        __syncthreads();   // B2: tiles staged

        // ---- matmul1: S^T blocks. st4[tb] = K[tb-block] @ Q-stripe^T ----
        f32x4 st4[4];
        #pragma unroll
        for (int tb = 0; tb < 4; tb++) st4[tb] = (f32x4){0.f,0.f,0.f,0.f};
        #pragma unroll
        for (int ks = 0; ks < 2; ks++){
            #pragma unroll
            for (int tb = 0; tb < 4; tb++){
                bf16x8 af = *(const bf16x8*)&kt[(16*tb + lq)*KSTR + 32*ks + 8*quad];
                st4[tb] = __builtin_amdgcn_mfma_f32_16x16x32_bf16(af, qf[ks], st4[tb], 0, 0, 0);
            }
        }

        // ---- decay + causal mask + online softmax (per s=lq) ----
        bool diag = (t0 == s0);
        float dv[4][4];
        float pmax = -INFINITY;
        #pragma unroll
        for (int tb = 0; tb < 4; tb++){
            float4 c4 = *(const float4*)&cumL[16*tb + 4*quad];
            float4 g4 = *(const float4*)&igL[16*tb + 4*quad];
            float cc[4] = {c4.x, c4.y, c4.z, c4.w};
            float gg[4] = {g4.x, g4.y, g4.z, g4.w};
            #pragma unroll
            for (int r = 0; r < 4; r++){
                float d = cq - cc[r] + gg[r];
                if (diag && (t0 + 16*tb + 4*quad + r) > s_glob) d = -INFINITY;
                dv[tb][r] = d;
                pmax = fmaxf(pmax, d);
            }
        }
        pmax = fmaxf(pmax, __shfl_xor(pmax, 16, 64));
        pmax = fmaxf(pmax, __shfl_xor(pmax, 32, 64));
        float mn = fmaxf(m_s, pmax);
        float sc = exp2f((m_s - mn) * LOG2E);   // first tile: exp2(-inf)=0
        m_s = mn;
        float rs = 0.f;
        bf16x4 pf[4];   // P^T in 16x16x16 A-operand layout: A[m=lq][k=4quad+j]
        #pragma unroll
        for (int tb = 0; tb < 4; tb++){
            #pragma unroll
            for (int r = 0; r < 4; r++){
                float pv = st4[tb][r] * exp2f((dv[tb][r] - mn) * LOG2E);
                rs += pv;
                pf[tb][r] = (short)f2bf(pv);
            }
        }
        rs += __shfl_xor(rs, 16, 64);
        rs += __shfl_xor(rs, 32, 64);
        b_s = b_s * sc + rs;

        // rescale O rows: O-row index is s=4quad+r; sc lives on lanes with lq=4quad+r
        #pragma unroll
        for (int r = 0; r < 4; r++){
            float sco = __shfl(sc, 20*quad + r, 64);   // src lane lq = 4quad+r
            #pragma unroll
            for (int cg = 0; cg < 4; cg++) oacc[cg][r] *= sco;
        }

        // ---- matmul2: O += P @ V via 16x16x16 (A=pf in-register, B from vt) ----
        #pragma unroll
        for (int tb = 0; tb < 4; tb++){
            #pragma unroll
            for (int cg = 0; cg < 4; cg++){
                bf16x4 vf = *(const bf16x4*)&vt[(16*cg + lq)*KSTR + 16*tb + 4*quad];
                oacc[cg] = __builtin_amdgcn_mfma_f32_16x16x16bf16_1k(pf[tb], vf, oacc[cg], 0, 0, 0);
            }
        }
    }

    // ---- epilogue: normalizer + per-head LayerNorm + scale ----
    #pragma unroll
    for (int r = 0; r < 4; r++){
        float bo = __shfl(b_s, 20*quad + r, 64);
        float mo = __shfl(m_s, 20*quad + r, 64);
        float nrm = fmaxf(fabsf(bo), exp2f(-mo * LOG2E));
        float inv = 1.f / (nrm + EPS);
        float x[4];
        float s1 = 0.f, s2 = 0.f;
        #pragma unroll
        for (int cg = 0; cg < 4; cg++){
            x[cg] = oacc[cg][r] * inv;
            s1 += x[cg]; s2 += x[cg]*x[cg];
        }
        #pragma unroll
        for (int off = 8; off >= 1; off >>= 1){
            s1 += __shfl_xor(s1, off, 64);
            s2 += __shfl_xor(s2, off, 64);
        }
        float mean = s1 * (1.f/64.f);
        float var  = s2 * (1.f/64.f) - mean*mean;
        float rstd = rsqrtf(var + LN_EPS);
        size_t orow = ((size_t)b*S_ + s0 + 16*wv + 4*quad + r)*DIM + h*DH;
        #pragma unroll
        for (int cg = 0; cg < 4; cg++)
            out[orow + 16*cg + lq] = (x[cg] - mean) * rstd * (1.f + wld[cg]);
    }
}

extern "C" void kernel_launch(void* const* d_in, const int* in_sizes, int n_in,
                              void* d_out, int out_size, void* d_ws, size_t ws_size,
                              hipStream_t stream) {
    const float* q  = (const float*)d_in[0];
    const float* k  = (const float*)d_in[1];
    const float* v  = (const float*)d_in[2];
    const float* iw = (const float*)d_in[3];
    const float* ib = (const float*)d_in[4];
    const float* fw = (const float*)d_in[5];
    const float* fb = (const float*)d_in[6];
    const float* w  = (const float*)d_in[7];
    float* out = (float*)d_out;

    float* ig  = (float*)d_ws;                 // B*NH*S
    float* lf  = ig  + (size_t)B_*NH*S_;       // B*NH*S
    float* cum = lf  + (size_t)B_*NH*S_;       // B*NH*S

    gates_kernel<<<B_*S_/4, 256, 0, stream>>>(q, k, v, iw, ib, fw, fb, ig, lf);
    scan_kernel<<<B_*NH, 256, 0, stream>>>(lf, cum);
    mlstm_kernel<<<dim3(S_/64, B_*NH), 256, 0, stream>>>(q, k, v, ig, cum, w, out);
}

// Round 5
// 178.170 us; speedup vs baseline: 2.2425x; 1.3225x over previous
//
#include <hip/hip_runtime.h>
#include <math.h>

#define DIM 384
#define NH 6
#define DH 64
#define B_ 2
#define S_ 2048
#define EPS 1e-6f
#define LN_EPS 1e-5f
#define G3 (3*DIM)   // 1152
#define LOG2E 1.44269504f
#define KSTR 72      // LDS row stride (ushort): 144 B -> 4-bank rotate/row
#define NT (S_/64)   // 32 q-tiles per (b,h)

typedef __attribute__((ext_vector_type(8))) short bf16x8;
typedef __attribute__((ext_vector_type(4))) short bf16x4;
typedef __attribute__((ext_vector_type(4))) float f32x4;

__device__ __forceinline__ unsigned short f2bf(float f){
    unsigned int u = __float_as_uint(f);
    u += 0x7fff + ((u >> 16) & 1);   // round-to-nearest-even
    return (unsigned short)(u >> 16);
}

__device__ __forceinline__ float logsig(float x){
    return fminf(x, 0.f) - log1pf(expf(-fabsf(x)));
}

// ---------------- Kernel 1: gate projections ----------------
__global__ __launch_bounds__(256) void gates_kernel(
    const float* __restrict__ q, const float* __restrict__ k, const float* __restrict__ v,
    const float* __restrict__ iw, const float* __restrict__ ib,
    const float* __restrict__ fw, const float* __restrict__ fb,
    float* __restrict__ ig_out, float* __restrict__ lf_out) {
    int wave = (blockIdx.x * 256 + threadIdx.x) >> 6;
    int lane = threadIdx.x & 63;
    int b = wave / S_, s = wave % S_;
    size_t base = ((size_t)b * S_ + s) * DIM;
    float aI[NH], aF[NH];
    #pragma unroll
    for (int h = 0; h < NH; h++){ aI[h] = 0.f; aF[h] = 0.f; }
    for (int e = lane; e < G3; e += 64) {
        float x;
        if (e < DIM)        x = q[base + e];
        else if (e < 2*DIM) x = k[base + e - DIM];
        else                x = v[base + e - 2*DIM];
        #pragma unroll
        for (int h = 0; h < NH; h++){
            aI[h] = fmaf(x, iw[h*G3 + e], aI[h]);
            aF[h] = fmaf(x, fw[h*G3 + e], aF[h]);
        }
    }
    #pragma unroll
    for (int h = 0; h < NH; h++){
        #pragma unroll
        for (int off = 32; off >= 1; off >>= 1){
            aI[h] += __shfl_xor(aI[h], off, 64);
            aF[h] += __shfl_xor(aF[h], off, 64);
        }
    }
    if (lane == 0) {
        #pragma unroll
        for (int h = 0; h < NH; h++){
            ig_out[((size_t)b*NH + h)*S_ + s] = aI[h] + ib[h];
            lf_out[((size_t)b*NH + h)*S_ + s] = logsig(aF[h] + fb[h]);
        }
    }
}

// ---------------- Kernel 2: cumsum of log-sigmoid(fgate) ----------------
__global__ __launch_bounds__(256) void scan_kernel(const float* __restrict__ lf,
                                                   float* __restrict__ cum){
    int bh = blockIdx.x;
    const float* src = lf + (size_t)bh * S_;
    float* dst = cum + (size_t)bh * S_;
    int tid = threadIdx.x;
    float loc[8];
    float run = 0.f;
    #pragma unroll
    for (int j = 0; j < 8; j++){ run += src[tid*8 + j]; loc[j] = run; }
    __shared__ float sm[256];
    sm[tid] = run;
    __syncthreads();
    float total = run;
    for (int off = 1; off < 256; off <<= 1){
        float vv = (tid >= off) ? sm[tid - off] : 0.f;
        __syncthreads();
        sm[tid] += vv;
        __syncthreads();
    }
    float excl = sm[tid] - total;
    #pragma unroll
    for (int j = 0; j < 8; j++) dst[tid*8 + j] = excl + loc[j];
}

// ---------------- Kernel 3: MFMA flash-mLSTM (transpose-free, pipelined) -----
// Block = 256 = 4 waves; wave wv owns q-rows [s0+16wv, s0+16wv+16).
// Matmul1 computes S^T = MFMA(A=K-block, B=Q-stripe); the exp-ed P^T values
// are directly the 16x16x16 A-operand layout for PV -> no LDS transpose
// (round-2/3 tripwire root cause eliminated).
// Block swizzle: linear id, st descending -> the 12 longest blocks get
// consecutive dispatch ids (spread across the 8 XCDs) instead of all
// landing on XCD 0 (ids = 0 mod 32 in the round-4 layout).
// Staging is register-prefetched: loads for tile t+1 issue right after B2,
// overlapping the whole compute phase of tile t.
__global__ __launch_bounds__(256) void mlstm_kernel(
    const float* __restrict__ q, const float* __restrict__ k, const float* __restrict__ v,
    const float* __restrict__ ig, const float* __restrict__ cum,
    const float* __restrict__ w, float* __restrict__ out) {
    __shared__ unsigned short kt[64*KSTR];   // K row-major: kt[t][d]
    __shared__ unsigned short vt[64*KSTR];   // V transposed: vt[d][t]
    __shared__ float cumL[64];
    __shared__ float igL[64];

    int lin = blockIdx.x + gridDim.x * blockIdx.y;   // 0..383
    int st  = (NT - 1) - (lin / (B_*NH));            // longest first, ids spread
    int bh  = lin % (B_*NH);
    int b = bh / NH, h = bh % NH;
    int s0 = st * 64;
    int tid = threadIdx.x;
    int wv   = tid >> 6;
    int lane = tid & 63;
    int lq   = lane & 15;
    int quad = lane >> 4;

    const float* qbase = q + (size_t)b*S_*DIM + h*DH;
    const float* kbase = k + (size_t)b*S_*DIM + h*DH;
    const float* vbase = v + (size_t)b*S_*DIM + h*DH;
    const float* igb = ig + (size_t)bh*S_;
    const float* cmb = cum + (size_t)bh*S_;

    int s_glob = s0 + 16*wv + lq;   // the s-row this lane's softmax state tracks

    // Q as B-operand fragments: B[n=lq][k=quad*8+j], rows s0+16wv+lq, x0.125
    bf16x8 qf[2];
    {
        const float* qr = qbase + (size_t)s_glob*DIM;
        #pragma unroll
        for (int ks = 0; ks < 2; ks++){
            float4 a = *(const float4*)(qr + 32*ks + 8*quad);
            float4 c = *(const float4*)(qr + 32*ks + 8*quad + 4);
            bf16x8 t;
            t[0]=(short)f2bf(a.x*0.125f); t[1]=(short)f2bf(a.y*0.125f);
            t[2]=(short)f2bf(a.z*0.125f); t[3]=(short)f2bf(a.w*0.125f);
            t[4]=(short)f2bf(c.x*0.125f); t[5]=(short)f2bf(c.y*0.125f);
            t[6]=(short)f2bf(c.z*0.125f); t[7]=(short)f2bf(c.w*0.125f);
            qf[ks] = t;
        }
    }

    float cq  = cmb[s_glob];
    float m_s = -INFINITY, b_s = 0.f;   // online-softmax state for row s=lq
    f32x4 oacc[4];                      // O C-layout: row s=4quad+r, col d=16cg+lq
    #pragma unroll
    for (int cg = 0; cg < 4; cg++) oacc[cg] = (f32x4){0.f,0.f,0.f,0.f};
    float wld[4];
    #pragma unroll
    for (int cg = 0; cg < 4; cg++) wld[cg] = w[h*DH + 16*cg + lq];

    // staging addresses for this thread (4 rows x 1 float4 each for K and V)
    int srow[4], scol[4];
    #pragma unroll
    for (int i = 0; i < 4; i++){
        int idx = tid + 256*i;
        srow[i] = idx >> 4;          // tile row (t)
        scol[i] = (idx & 15) << 2;   // col (d), x4
    }

    float4 kreg[4], vreg[4];
    // preload tile 0
    #pragma unroll
    for (int i = 0; i < 4; i++){
        kreg[i] = *(const float4*)(kbase + (size_t)srow[i]*DIM + scol[i]);
        vreg[i] = *(const float4*)(vbase + (size_t)srow[i]*DIM + scol[i]);
    }

    for (int t0 = 0; t0 <= s0; t0 += 64){
        __syncthreads();   // B1: prev iteration done reading kt/vt/cumL/igL
        // ---- store prefetched tile t0 to LDS (K row-major, V transposed) ----
        #pragma unroll
        for (int i = 0; i < 4; i++){
            int r = srow[i], c = scol[i];
            ushort4 kk; kk.x=f2bf(kreg[i].x); kk.y=f2bf(kreg[i].y);
            kk.z=f2bf(kreg[i].z); kk.w=f2bf(kreg[i].w);
            *(ushort4*)&kt[r*KSTR + c] = kk;
            vt[(c+0)*KSTR + r] = f2bf(vreg[i].x);
            vt[(c+1)*KSTR + r] = f2bf(vreg[i].y);
            vt[(c+2)*KSTR + r] = f2bf(vreg[i].z);
            vt[(c+3)*KSTR + r] = f2bf(vreg[i].w);
        }
        if (tid < 64){ cumL[tid] = cmb[t0 + tid]; igL[tid] = igb[t0 + tid]; }
        __syncthreads();   // B2: tiles staged

        // ---- issue prefetch for tile t0+64 (overlaps compute below) ----
        if (t0 + 64 <= s0){
            const float* kb = kbase + (size_t)(t0 + 64)*DIM;
            const float* vb = vbase + (size_t)(t0 + 64)*DIM;
            #pragma unroll
            for (int i = 0; i < 4; i++){
                kreg[i] = *(const float4*)(kb + (size_t)srow[i]*DIM + scol[i]);
                vreg[i] = *(const float4*)(vb + (size_t)srow[i]*DIM + scol[i]);
            }
        }

        // ---- matmul1: S^T blocks. st4[tb] = K[tb-block] @ Q-stripe^T ----
        f32x4 st4[4];
        #pragma unroll
        for (int tb = 0; tb < 4; tb++) st4[tb] = (f32x4){0.f,0.f,0.f,0.f};
        #pragma unroll
        for (int ks = 0; ks < 2; ks++){
            #pragma unroll
            for (int tb = 0; tb < 4; tb++){
                bf16x8 af = *(const bf16x8*)&kt[(16*tb + lq)*KSTR + 32*ks + 8*quad];
                st4[tb] = __builtin_amdgcn_mfma_f32_16x16x32_bf16(af, qf[ks], st4[tb], 0, 0, 0);
            }
        }

        // ---- decay + causal mask + online softmax (per s=lq) ----
        bool diag = (t0 == s0);
        float dv[4][4];
        float pmax = -INFINITY;
        #pragma unroll
        for (int tb = 0; tb < 4; tb++){
            float4 c4 = *(const float4*)&cumL[16*tb + 4*quad];
            float4 g4 = *(const float4*)&igL[16*tb + 4*quad];
            float cc[4] = {c4.x, c4.y, c4.z, c4.w};
            float gg[4] = {g4.x, g4.y, g4.z, g4.w};
            #pragma unroll
            for (int r = 0; r < 4; r++){
                float d = cq - cc[r] + gg[r];
                if (diag && (t0 + 16*tb + 4*quad + r) > s_glob) d = -INFINITY;
                dv[tb][r] = d;
                pmax = fmaxf(pmax, d);
            }
        }
        pmax = fmaxf(pmax, __shfl_xor(pmax, 16, 64));
        pmax = fmaxf(pmax, __shfl_xor(pmax, 32, 64));
        float mn = fmaxf(m_s, pmax);
        float sc = exp2f((m_s - mn) * LOG2E);   // first tile: exp2(-inf)=0
        m_s = mn;
        float rs = 0.f;
        bf16x4 pf[4];   // P^T in 16x16x16 A-operand layout: A[m=lq][k=4quad+j]
        #pragma unroll
        for (int tb = 0; tb < 4; tb++){
            #pragma unroll
            for (int r = 0; r < 4; r++){
                float pv = st4[tb][r] * exp2f((dv[tb][r] - mn) * LOG2E);
                rs += pv;
                pf[tb][r] = (short)f2bf(pv);
            }
        }
        rs += __shfl_xor(rs, 16, 64);
        rs += __shfl_xor(rs, 32, 64);
        b_s = b_s * sc + rs;

        // rescale O rows: O-row index is s=4quad+r; sc lives on lanes lq=4quad+r
        #pragma unroll
        for (int r = 0; r < 4; r++){
            float sco = __shfl(sc, 20*quad + r, 64);
            #pragma unroll
            for (int cg = 0; cg < 4; cg++) oacc[cg][r] *= sco;
        }

        // ---- matmul2: O += P @ V via 16x16x16 (A=pf in-register, B from vt) --
        #pragma unroll
        for (int tb = 0; tb < 4; tb++){
            #pragma unroll
            for (int cg = 0; cg < 4; cg++){
                bf16x4 vf = *(const bf16x4*)&vt[(16*cg + lq)*KSTR + 16*tb + 4*quad];
                oacc[cg] = __builtin_amdgcn_mfma_f32_16x16x16bf16_1k(pf[tb], vf, oacc[cg], 0, 0, 0);
            }
        }
    }

    // ---- epilogue: normalizer + per-head LayerNorm + scale ----
    #pragma unroll
    for (int r = 0; r < 4; r++){
        float bo = __shfl(b_s, 20*quad + r, 64);
        float mo = __shfl(m_s, 20*quad + r, 64);
        float nrm = fmaxf(fabsf(bo), exp2f(-mo * LOG2E));
        float inv = 1.f / (nrm + EPS);
        float x[4];
        float s1 = 0.f, s2 = 0.f;
        #pragma unroll
        for (int cg = 0; cg < 4; cg++){
            x[cg] = oacc[cg][r] * inv;
            s1 += x[cg]; s2 += x[cg]*x[cg];
        }
        #pragma unroll
        for (int off = 8; off >= 1; off >>= 1){
            s1 += __shfl_xor(s1, off, 64);
            s2 += __shfl_xor(s2, off, 64);
        }
        float mean = s1 * (1.f/64.f);
        float var  = s2 * (1.f/64.f) - mean*mean;
        float rstd = rsqrtf(var + LN_EPS);
        size_t orow = ((size_t)b*S_ + s0 + 16*wv + 4*quad + r)*DIM + h*DH;
        #pragma unroll
        for (int cg = 0; cg < 4; cg++)
            out[orow + 16*cg + lq] = (x[cg] - mean) * rstd * (1.f + wld[cg]);
    }
}

extern "C" void kernel_launch(void* const* d_in, const int* in_sizes, int n_in,
                              void* d_out, int out_size, void* d_ws, size_t ws_size,
                              hipStream_t stream) {
    const float* q  = (const float*)d_in[0];
    const float* k  = (const float*)d_in[1];
    const float* v  = (const float*)d_in[2];
    const float* iw = (const float*)d_in[3];
    const float* ib = (const float*)d_in[4];
    const float* fw = (const float*)d_in[5];
    const float* fb = (const float*)d_in[6];
    const float* w  = (const float*)d_in[7];
    float* out = (float*)d_out;

    float* ig  = (float*)d_ws;                 // B*NH*S
    float* lf  = ig  + (size_t)B_*NH*S_;       // B*NH*S
    float* cum = lf  + (size_t)B_*NH*S_;       // B*NH*S

    gates_kernel<<<B_*S_/4, 256, 0, stream>>>(q, k, v, iw, ib, fw, fb, ig, lf);
    scan_kernel<<<B_*NH, 256, 0, stream>>>(lf, cum);
    mlstm_kernel<<<dim3(NT, B_*NH), 256, 0, stream>>>(q, k, v, ig, cum, w, out);
}

// Round 6
// 140.827 us; speedup vs baseline: 2.8371x; 1.2652x over previous
//
#include <hip/hip_runtime.h>
#include <math.h>

#define DIM 384
#define NH 6
#define DH 64
#define B_ 2
#define S_ 2048
#define EPS 1e-6f
#define LN_EPS 1e-5f
#define G3 (3*DIM)   // 1152
#define LOG2E 1.44269504f
#define KSTR 72      // LDS row stride (ushort): 144 B -> 4-bank rotate/row
#define NT (S_/64)   // 32 q-tiles per (b,h)
#define NSPLIT 4     // t-range splits per q-tile (flash-decoding)
#define NBH (B_*NH)  // 12

typedef __attribute__((ext_vector_type(8))) short bf16x8;
typedef __attribute__((ext_vector_type(4))) short bf16x4;
typedef __attribute__((ext_vector_type(4))) float f32x4;

__device__ __forceinline__ unsigned short f2bf(float f){
    unsigned int u = __float_as_uint(f);
    u += 0x7fff + ((u >> 16) & 1);   // round-to-nearest-even
    return (unsigned short)(u >> 16);
}

__device__ __forceinline__ float logsig(float x){
    return fminf(x, 0.f) - log1pf(expf(-fabsf(x)));
}

// ---------------- Kernel 1: gate projections ----------------
__global__ __launch_bounds__(256) void gates_kernel(
    const float* __restrict__ q, const float* __restrict__ k, const float* __restrict__ v,
    const float* __restrict__ iw, const float* __restrict__ ib,
    const float* __restrict__ fw, const float* __restrict__ fb,
    float* __restrict__ ig_out, float* __restrict__ lf_out) {
    int wave = (blockIdx.x * 256 + threadIdx.x) >> 6;
    int lane = threadIdx.x & 63;
    int b = wave / S_, s = wave % S_;
    size_t base = ((size_t)b * S_ + s) * DIM;
    float aI[NH], aF[NH];
    #pragma unroll
    for (int h = 0; h < NH; h++){ aI[h] = 0.f; aF[h] = 0.f; }
    for (int e = lane; e < G3; e += 64) {
        float x;
        if (e < DIM)        x = q[base + e];
        else if (e < 2*DIM) x = k[base + e - DIM];
        else                x = v[base + e - 2*DIM];
        #pragma unroll
        for (int h = 0; h < NH; h++){
            aI[h] = fmaf(x, iw[h*G3 + e], aI[h]);
            aF[h] = fmaf(x, fw[h*G3 + e], aF[h]);
        }
    }
    #pragma unroll
    for (int h = 0; h < NH; h++){
        #pragma unroll
        for (int off = 32; off >= 1; off >>= 1){
            aI[h] += __shfl_xor(aI[h], off, 64);
            aF[h] += __shfl_xor(aF[h], off, 64);
        }
    }
    if (lane == 0) {
        #pragma unroll
        for (int h = 0; h < NH; h++){
            ig_out[((size_t)b*NH + h)*S_ + s] = aI[h] + ib[h];
            lf_out[((size_t)b*NH + h)*S_ + s] = logsig(aF[h] + fb[h]);
        }
    }
}

// ---------------- Kernel 2: cumsum of log-sigmoid(fgate) ----------------
__global__ __launch_bounds__(256) void scan_kernel(const float* __restrict__ lf,
                                                   float* __restrict__ cum){
    int bh = blockIdx.x;
    const float* src = lf + (size_t)bh * S_;
    float* dst = cum + (size_t)bh * S_;
    int tid = threadIdx.x;
    float loc[8];
    float run = 0.f;
    #pragma unroll
    for (int j = 0; j < 8; j++){ run += src[tid*8 + j]; loc[j] = run; }
    __shared__ float sm[256];
    sm[tid] = run;
    __syncthreads();
    float total = run;
    for (int off = 1; off < 256; off <<= 1){
        float vv = (tid >= off) ? sm[tid - off] : 0.f;
        __syncthreads();
        sm[tid] += vv;
        __syncthreads();
    }
    float excl = sm[tid] - total;
    #pragma unroll
    for (int j = 0; j < 8; j++) dst[tid*8 + j] = excl + loc[j];
}

// ---------------- Kernel 3a: split-T partial flash-mLSTM ----------------
// Each q-tile's causal t-range is cut into NSPLIT=4 splits of L=ceil((st+1)/4)
// t-tiles; one 4-wave block per split (<=8 iterations serial critical path,
// was 32). Partials (m-hat, l-hat, O-hat 64x64 fp32) go to workspace.
// Transpose-free S^T formulation (rounds 2-4 tripwire post-mortem).
__global__ __launch_bounds__(256) void mlstm_part(
    const float* __restrict__ q, const float* __restrict__ k, const float* __restrict__ v,
    const float* __restrict__ ig, const float* __restrict__ cum,
    float* __restrict__ pO, float* __restrict__ pM, float* __restrict__ pL) {
    int lin = blockIdx.x;            // 0..NBH*NT*NSPLIT-1
    int sp  = lin / NBH;             // 0..127: split-slot, longest q-tiles first
    int bh  = lin % NBH;
    int st  = (NT - 1) - (sp >> 2);
    int c   = sp & 3;
    int L   = (st + 4) >> 2;         // ceil((st+1)/4)
    int tb0 = c * L;
    int tb1 = min((c + 1) * L, st + 1);
    int pblk = lin;
    int tid = threadIdx.x;

    if (tb0 >= tb1){                 // empty split: neutral partial, exit
        if (tid < 64){ pM[pblk*64 + tid] = -INFINITY; pL[pblk*64 + tid] = 0.f; }
        return;
    }

    __shared__ unsigned short kt[64*KSTR];   // K row-major: kt[t][d]
    __shared__ unsigned short vt[64*KSTR];   // V transposed: vt[d][t]
    __shared__ float cumL[64];
    __shared__ float igL[64];

    int b = bh / NH, h = bh % NH;
    int s0 = st * 64;
    int wv   = tid >> 6;
    int lane = tid & 63;
    int lq   = lane & 15;
    int quad = lane >> 4;

    const float* qbase = q + (size_t)b*S_*DIM + h*DH;
    const float* kbase = k + (size_t)b*S_*DIM + h*DH;
    const float* vbase = v + (size_t)b*S_*DIM + h*DH;
    const float* igb = ig + (size_t)bh*S_;
    const float* cmb = cum + (size_t)bh*S_;

    int s_glob = s0 + 16*wv + lq;    // s-row this lane's softmax state tracks

    // Q as B-operand fragments: B[n=lq][k=quad*8+j], x0.125
    bf16x8 qf[2];
    {
        const float* qr = qbase + (size_t)s_glob*DIM;
        #pragma unroll
        for (int ks = 0; ks < 2; ks++){
            float4 a = *(const float4*)(qr + 32*ks + 8*quad);
            float4 cc = *(const float4*)(qr + 32*ks + 8*quad + 4);
            bf16x8 t;
            t[0]=(short)f2bf(a.x*0.125f); t[1]=(short)f2bf(a.y*0.125f);
            t[2]=(short)f2bf(a.z*0.125f); t[3]=(short)f2bf(a.w*0.125f);
            t[4]=(short)f2bf(cc.x*0.125f); t[5]=(short)f2bf(cc.y*0.125f);
            t[6]=(short)f2bf(cc.z*0.125f); t[7]=(short)f2bf(cc.w*0.125f);
            qf[ks] = t;
        }
    }

    float cq  = cmb[s_glob];
    float m_s = -INFINITY, b_s = 0.f;
    f32x4 oacc[4];                   // O C-layout: row s=4quad+r, col d=16cg+lq
    #pragma unroll
    for (int cg = 0; cg < 4; cg++) oacc[cg] = (f32x4){0.f,0.f,0.f,0.f};

    int srow[4], scol[4];
    #pragma unroll
    for (int i = 0; i < 4; i++){
        int idx = tid + 256*i;
        srow[i] = idx >> 4;
        scol[i] = (idx & 15) << 2;
    }

    float4 kreg[4], vreg[4];
    {
        const float* kb = kbase + (size_t)(tb0*64)*DIM;
        const float* vb = vbase + (size_t)(tb0*64)*DIM;
        #pragma unroll
        for (int i = 0; i < 4; i++){
            kreg[i] = *(const float4*)(kb + (size_t)srow[i]*DIM + scol[i]);
            vreg[i] = *(const float4*)(vb + (size_t)srow[i]*DIM + scol[i]);
        }
    }

    for (int t0 = tb0*64; t0 < tb1*64; t0 += 64){
        __syncthreads();   // B1: prev iteration done reading kt/vt/cumL/igL
        #pragma unroll
        for (int i = 0; i < 4; i++){
            int r = srow[i], cc = scol[i];
            ushort4 kk; kk.x=f2bf(kreg[i].x); kk.y=f2bf(kreg[i].y);
            kk.z=f2bf(kreg[i].z); kk.w=f2bf(kreg[i].w);
            *(ushort4*)&kt[r*KSTR + cc] = kk;
            vt[(cc+0)*KSTR + r] = f2bf(vreg[i].x);
            vt[(cc+1)*KSTR + r] = f2bf(vreg[i].y);
            vt[(cc+2)*KSTR + r] = f2bf(vreg[i].z);
            vt[(cc+3)*KSTR + r] = f2bf(vreg[i].w);
        }
        if (tid < 64){ cumL[tid] = cmb[t0 + tid]; igL[tid] = igb[t0 + tid]; }
        __syncthreads();   // B2: tiles staged

        // prefetch next tile of this split (overlaps compute)
        if (t0 + 64 < tb1*64){
            const float* kb = kbase + (size_t)(t0 + 64)*DIM;
            const float* vb = vbase + (size_t)(t0 + 64)*DIM;
            #pragma unroll
            for (int i = 0; i < 4; i++){
                kreg[i] = *(const float4*)(kb + (size_t)srow[i]*DIM + scol[i]);
                vreg[i] = *(const float4*)(vb + (size_t)srow[i]*DIM + scol[i]);
            }
        }

        // ---- matmul1: S^T blocks ----
        f32x4 st4[4];
        #pragma unroll
        for (int tb = 0; tb < 4; tb++) st4[tb] = (f32x4){0.f,0.f,0.f,0.f};
        #pragma unroll
        for (int ks = 0; ks < 2; ks++){
            #pragma unroll
            for (int tb = 0; tb < 4; tb++){
                bf16x8 af = *(const bf16x8*)&kt[(16*tb + lq)*KSTR + 32*ks + 8*quad];
                st4[tb] = __builtin_amdgcn_mfma_f32_16x16x32_bf16(af, qf[ks], st4[tb], 0, 0, 0);
            }
        }

        // ---- decay + causal mask + online softmax (per s=lq) ----
        bool diag = (t0 == s0);
        float dv[4][4];
        float pmax = -INFINITY;
        #pragma unroll
        for (int tb = 0; tb < 4; tb++){
            float4 c4 = *(const float4*)&cumL[16*tb + 4*quad];
            float4 g4 = *(const float4*)&igL[16*tb + 4*quad];
            float ccv[4] = {c4.x, c4.y, c4.z, c4.w};
            float gg[4] = {g4.x, g4.y, g4.z, g4.w};
            #pragma unroll
            for (int r = 0; r < 4; r++){
                float d = cq - ccv[r] + gg[r];
                if (diag && (t0 + 16*tb + 4*quad + r) > s_glob) d = -INFINITY;
                dv[tb][r] = d;
                pmax = fmaxf(pmax, d);
            }
        }
        pmax = fmaxf(pmax, __shfl_xor(pmax, 16, 64));
        pmax = fmaxf(pmax, __shfl_xor(pmax, 32, 64));
        float mn = fmaxf(m_s, pmax);
        float sc = exp2f((m_s - mn) * LOG2E);
        m_s = mn;
        float rs = 0.f;
        bf16x4 pf[4];   // P^T in 16x16x16 A-operand layout
        #pragma unroll
        for (int tb = 0; tb < 4; tb++){
            #pragma unroll
            for (int r = 0; r < 4; r++){
                float pv = st4[tb][r] * exp2f((dv[tb][r] - mn) * LOG2E);
                rs += pv;
                pf[tb][r] = (short)f2bf(pv);
            }
        }
        rs += __shfl_xor(rs, 16, 64);
        rs += __shfl_xor(rs, 32, 64);
        b_s = b_s * sc + rs;

        #pragma unroll
        for (int r = 0; r < 4; r++){
            float sco = __shfl(sc, 20*quad + r, 64);
            #pragma unroll
            for (int cg = 0; cg < 4; cg++) oacc[cg][r] *= sco;
        }

        // ---- matmul2: O += P @ V ----
        #pragma unroll
        for (int tb = 0; tb < 4; tb++){
            #pragma unroll
            for (int cg = 0; cg < 4; cg++){
                bf16x4 vf = *(const bf16x4*)&vt[(16*cg + lq)*KSTR + 16*tb + 4*quad];
                oacc[cg] = __builtin_amdgcn_mfma_f32_16x16x16bf16_1k(pf[tb], vf, oacc[cg], 0, 0, 0);
            }
        }
    }

    // ---- write partials ----
    float* po = pO + (size_t)pblk * 4096;
    #pragma unroll
    for (int r = 0; r < 4; r++){
        int row = 16*wv + 4*quad + r;
        #pragma unroll
        for (int cg = 0; cg < 4; cg++)
            po[row*64 + 16*cg + lq] = oacc[cg][r];
    }
    if (quad == 0){
        pM[pblk*64 + 16*wv + lq] = m_s;
        pL[pblk*64 + 16*wv + lq] = b_s;
    }
}

// ---------------- Kernel 3b: combine partials + normalizer + LayerNorm -------
// One block per q-tile; merge <=4 split partials with exp-weights, then
// normalizer + per-head LayerNorm + scale.
__global__ __launch_bounds__(256) void mlstm_combine(
    const float* __restrict__ pO, const float* __restrict__ pM,
    const float* __restrict__ pL, const float* __restrict__ w,
    float* __restrict__ out) {
    int st = blockIdx.x;
    int bh = blockIdx.y;
    int b = bh / NH, h = bh % NH;
    int tid = threadIdx.x;
    int cl = (tid & 15) * 4;       // col base (float4)
    int rb = tid >> 4;             // row within 16-row band

    int pblk[NSPLIT];
    #pragma unroll
    for (int p = 0; p < NSPLIT; p++)
        pblk[p] = (((NT - 1 - st) << 2) + p) * NBH + bh;

    float4 wv4 = *(const float4*)(w + h*DH + cl);

    #pragma unroll
    for (int pass = 0; pass < 4; pass++){
        int row = pass*16 + rb;
        float mp[NSPLIT], lp[NSPLIT];
        float mmax = -INFINITY;
        #pragma unroll
        for (int p = 0; p < NSPLIT; p++){
            mp[p] = pM[pblk[p]*64 + row];
            lp[p] = pL[pblk[p]*64 + row];
            mmax = fmaxf(mmax, mp[p]);
        }
        float l = 0.f;
        float4 o = {0.f, 0.f, 0.f, 0.f};
        #pragma unroll
        for (int p = 0; p < NSPLIT; p++){
            float wp = exp2f((mp[p] - mmax) * LOG2E);   // empty split: 0
            l += wp * lp[p];
            float4 t = *(const float4*)(pO + (size_t)pblk[p]*4096 + row*64 + cl);
            o.x += wp*t.x; o.y += wp*t.y; o.z += wp*t.z; o.w += wp*t.w;
        }
        float nrm = fmaxf(fabsf(l), exp2f(-mmax * LOG2E));
        float inv = 1.f / (nrm + EPS);
        float x[4] = {o.x*inv, o.y*inv, o.z*inv, o.w*inv};
        float s1 = x[0]+x[1]+x[2]+x[3];
        float s2 = x[0]*x[0]+x[1]*x[1]+x[2]*x[2]+x[3]*x[3];
        #pragma unroll
        for (int off = 8; off >= 1; off >>= 1){
            s1 += __shfl_xor(s1, off, 64);
            s2 += __shfl_xor(s2, off, 64);
        }
        float mean = s1 * (1.f/64.f);
        float var  = s2 * (1.f/64.f) - mean*mean;
        float rstd = rsqrtf(var + LN_EPS);
        float4 oo;
        oo.x = (x[0]-mean)*rstd*(1.f + wv4.x);
        oo.y = (x[1]-mean)*rstd*(1.f + wv4.y);
        oo.z = (x[2]-mean)*rstd*(1.f + wv4.z);
        oo.w = (x[3]-mean)*rstd*(1.f + wv4.w);
        *(float4*)(out + ((size_t)b*S_ + st*64 + row)*DIM + h*DH + cl) = oo;
    }
}

extern "C" void kernel_launch(void* const* d_in, const int* in_sizes, int n_in,
                              void* d_out, int out_size, void* d_ws, size_t ws_size,
                              hipStream_t stream) {
    const float* q  = (const float*)d_in[0];
    const float* k  = (const float*)d_in[1];
    const float* v  = (const float*)d_in[2];
    const float* iw = (const float*)d_in[3];
    const float* ib = (const float*)d_in[4];
    const float* fw = (const float*)d_in[5];
    const float* fb = (const float*)d_in[6];
    const float* w  = (const float*)d_in[7];
    float* out = (float*)d_out;

    const int nPart = NBH * NT * NSPLIT;       // 1536
    float* ig  = (float*)d_ws;                 // B*NH*S
    float* lf  = ig  + (size_t)NBH*S_;         // B*NH*S
    float* cum = lf  + (size_t)NBH*S_;         // B*NH*S
    float* pM  = cum + (size_t)NBH*S_;         // nPart*64
    float* pL  = pM  + (size_t)nPart*64;       // nPart*64
    float* pO  = pL  + (size_t)nPart*64;       // nPart*4096  (~25 MB)

    gates_kernel<<<B_*S_/4, 256, 0, stream>>>(q, k, v, iw, ib, fw, fb, ig, lf);
    scan_kernel<<<NBH, 256, 0, stream>>>(lf, cum);
    mlstm_part<<<nPart, 256, 0, stream>>>(q, k, v, ig, cum, pO, pM, pL);
    mlstm_combine<<<dim3(NT, NBH), 256, 0, stream>>>(pO, pM, pL, w, out);
}